// Round 14
// baseline (135.176 us; speedup 1.0000x reference)
//
#include <hip/hip_runtime.h>

#define IN_DIM 128
#define OUT_DIM 64
#define PADK 136     // gemm LDS row stride (bf16 elems)
#define RB 64        // rows per bucket
#define RBSH 6       // log2(RB)
#define CAPB 1280    // bucket capacity (mean 1024, sigma 32 -> +8 sigma)
#define AB2 128      // afill blocks (fused; overlap with gemm)

typedef float f32x4 __attribute__((ext_vector_type(4)));
typedef short bf16x8 __attribute__((ext_vector_type(8)));

__device__ __forceinline__ unsigned short f2bf(float f) {   // RNE f32->bf16
    unsigned u = __float_as_uint(f);
    return (unsigned short)((u + 0x7FFFu + ((u >> 16) & 1u)) >> 16);
}
__device__ __forceinline__ float bf2f(unsigned short h) {
    return __uint_as_float((unsigned)h << 16);
}

// ---------------------------------------------------------------------------
// GEMM body: xw(bf16) = bf16(x)@bf16(W), single MFMA (no hi/lo split — the
// output is bf16-rounded anyway, so split precision was wasted; R13 lesson).
// LDS 34 KB (half of split version) -> 4 blocks/CU in the fused kernel.
// ---------------------------------------------------------------------------
__device__ __forceinline__ void gemm_body(const float* __restrict__ x,
                                          const float* __restrict__ w,
                                          unsigned short* __restrict__ xwb,
                                          int N, int blk,
                                          unsigned short* lds) {
    unsigned short* A = lds;                 // [64][PADK] bf16 x-tile
    unsigned short* B = lds + 64 * PADK;     // W^T: [c][k] bf16

    const int t = threadIdx.x;
    const int r0 = blk * 64;

    {   // stage W^T bf16
        const int c = t >> 2;
        const int kb = (t & 3) * 32;
        for (int k4 = 0; k4 < 32; k4 += 4) {
            ushort4 h;
            h.x = f2bf(w[(kb + k4 + 0) * OUT_DIM + c]);
            h.y = f2bf(w[(kb + k4 + 1) * OUT_DIM + c]);
            h.z = f2bf(w[(kb + k4 + 2) * OUT_DIM + c]);
            h.w = f2bf(w[(kb + k4 + 3) * OUT_DIM + c]);
            *(ushort4*)&B[c * PADK + kb + k4] = h;
        }
    }
    {   // stage x rows bf16
        const float4* x4 = (const float4*)x;
        for (int i = 0; i < 8; ++i) {
            const int f = i * 256 + t;
            const int rr = f >> 5;
            const int kk = (f & 31) * 4;
            int row = r0 + rr; if (row >= N) row = N - 1;
            float4 v = x4[(size_t)row * (IN_DIM / 4) + (kk >> 2)];
            ushort4 h;
            h.x = f2bf(v.x); h.y = f2bf(v.y); h.z = f2bf(v.z); h.w = f2bf(v.w);
            *(ushort4*)&A[rr * PADK + kk] = h;
        }
    }
    __syncthreads();

    const int lane = t & 63;
    const int wv = t >> 6;
    const int m = lane & 15;
    const int quad = lane >> 4;

    bf16x8 af[4];
#pragma unroll
    for (int ks = 0; ks < 4; ++ks)
        af[ks] = *(const bf16x8*)&A[(wv * 16 + m) * PADK + ks * 32 + quad * 8];
#pragma unroll
    for (int ct = 0; ct < 4; ++ct) {
        f32x4 acc = {0.f, 0.f, 0.f, 0.f};
#pragma unroll
        for (int ks = 0; ks < 4; ++ks) {
            bf16x8 bf = *(const bf16x8*)&B[(ct * 16 + m) * PADK + ks * 32 + quad * 8];
            acc = __builtin_amdgcn_mfma_f32_16x16x32_bf16(af[ks], bf, acc, 0, 0, 0);
        }
#pragma unroll
        for (int i = 0; i < 4; ++i) {
            const int row = r0 + wv * 16 + quad * 4 + i;
            if (row < N) xwb[(size_t)row * OUT_DIM + ct * 16 + m] = f2bf(acc[i]);
        }
    }
}

// ---------------------------------------------------------------------------
// afill body: bin edges into fixed-capacity 64-row buckets, GROUPED writes.
// LDS histogram -> one global cursor claim per (block,bucket) -> grouped
// stores in ~8-edge/64 B runs.  word0 = col | rowLocal<<16 (N <= 65536),
// word1 = fp32 val.  Slots beyond CAPB spill to olist (sized E: airtight).
// ---------------------------------------------------------------------------
__device__ __forceinline__ void afill_body(
        const int* __restrict__ arow, const int* __restrict__ acol,
        const float* __restrict__ aval, int* __restrict__ pcur,
        int* __restrict__ ocount, uint4* __restrict__ olist,
        uint2* __restrict__ payload, int E, int NB, int chunk, int blk,
        int* ldsi) {
    int* cnt  = ldsi;          // [1024]
    int* base = ldsi + 1024;   // [1024]   (8 KB, aliased into gemm LDS)
    const int t = threadIdx.x;
    const int lo = blk * chunk;
    const int hi = min(E, lo + chunk);
    if (lo >= hi) return;
    for (int i = t; i < NB; i += 256) cnt[i] = 0;
    __syncthreads();
    for (int e = lo + t; e < hi; e += 256)
        atomicAdd(&cnt[arow[e] >> RBSH], 1);
    __syncthreads();
    for (int i = t; i < NB; i += 256) {
        const int c = cnt[i];
        base[i] = c ? atomicAdd(&pcur[i], c) : 0;
        cnt[i] = 0;
    }
    __syncthreads();
    for (int e = lo + t; e < hi; e += 256) {
        const int r = arow[e];
        const int b = r >> RBSH;
        const int slot = base[b] + atomicAdd(&cnt[b], 1);
        const unsigned w0 = (unsigned)acol[e] | ((unsigned)(r & (RB - 1)) << 16);
        const unsigned w1 = __float_as_uint(aval[e]);
        if (slot < CAPB) {
            payload[(size_t)b * CAPB + slot] = make_uint2(w0, w1);
        } else {
            const int oi = atomicAdd(ocount, 1);   // olist sized E: always fits
            olist[oi] = make_uint4((unsigned)r, (unsigned)acol[e], w1, 0u);
        }
    }
}

// ---------------------------------------------------------------------------
// K1 fused: blocks [0,AB2) run afill (first in grid -> scheduling round 0,
// overlaps the gemm); blocks [AB2, AB2+GB) run the GEMM.  afill's 8 KB LDS
// aliases into the gemm's 34 KB buffer -> footprint 34 KB, 4 blocks/CU.
// ---------------------------------------------------------------------------
__global__ __launch_bounds__(256) void gemm_afill(
        const float* __restrict__ x, const float* __restrict__ w,
        unsigned short* __restrict__ xwb, int N,
        const int* __restrict__ arow, const int* __restrict__ acol,
        const float* __restrict__ aval, int* __restrict__ pcur,
        int* __restrict__ ocount, uint4* __restrict__ olist,
        uint2* __restrict__ payload, int E, int NB, int chunk) {
    __shared__ unsigned short LB[2 * 64 * PADK];   // 34 KB, shared by branches
    if ((int)blockIdx.x < AB2) {
        afill_body(arow, acol, aval, pcur, ocount, olist, payload, E, NB,
                   chunk, blockIdx.x, (int*)LB);
    } else {
        gemm_body(x, w, xwb, N, blockIdx.x - AB2, LB);
    }
}

__global__ __launch_bounds__(256) void gemm_only(const float* __restrict__ x,
                                                 const float* __restrict__ w,
                                                 unsigned short* __restrict__ xwb,
                                                 int N) {
    __shared__ unsigned short LB[2 * 64 * PADK];
    gemm_body(x, w, xwb, N, blockIdx.x, LB);
}

// ---------------------------------------------------------------------------
// bagg3: block b owns rows [64b, 64b+64).  Int-LDS counting sort by local
// row, then wave wv pulls rows [8wv, 8wv+8) into registers with 8-edge-ILP
// coalesced 128 B bf16 xw gathers.  Fused ReLU.  No fp32 atomics.
// ---------------------------------------------------------------------------
__global__ __launch_bounds__(512) void bagg3(
        const int* __restrict__ pcur, const uint2* __restrict__ payload,
        const unsigned short* __restrict__ xwb, float* __restrict__ out, int N,
        const int* __restrict__ ocount, const uint4* __restrict__ olist) {
    __shared__ uint2 stage[CAPB];       // 10 KB
    __shared__ int bins[RB + 1];
    __shared__ int pl[RB];
    const int t = threadIdx.x;
    const int lane = t & 63;
    const int wv = t >> 6;              // 0..7
    const int b = blockIdx.x;
    const int r0 = b << RBSH;

    const int cnt = min(pcur[b], CAPB); // payload filled contiguously [0,cnt)
    if (t <= RB) bins[t] = 0;
    if (t < RB) pl[t] = 0;
    __syncthreads();

    const uint2* pay = payload + (size_t)b * CAPB;
    for (int i = t; i < cnt; i += 512)
        atomicAdd(&bins[(pay[i].x >> 16) & (RB - 1)], 1);
    __syncthreads();
    if (t == 0) {                       // exclusive scan of 64 bins
        int run = 0;
        for (int i = 0; i < RB; ++i) { int v = bins[i]; bins[i] = run; run += v; }
        bins[RB] = run;
    }
    __syncthreads();
    for (int i = t; i < cnt; i += 512) {
        const uint2 e = pay[i];
        const int rl = (e.x >> 16) & (RB - 1);
        stage[bins[rl] + atomicAdd(&pl[rl], 1)] = e;
    }
    __syncthreads();

    float acc[8];
#pragma unroll
    for (int lr = 0; lr < 8; ++lr) {
        const int row = wv * 8 + lr;
        int j = bins[row];
        const int end = bins[row + 1];
        float a0 = 0.f, a1 = 0.f;
        for (; j + 8 <= end; j += 8) {
            uint2 e0 = stage[j],   e1 = stage[j+1], e2 = stage[j+2], e3 = stage[j+3];
            uint2 e4 = stage[j+4], e5 = stage[j+5], e6 = stage[j+6], e7 = stage[j+7];
            float g0 = bf2f(xwb[(size_t)(e0.x & 0xFFFF) * OUT_DIM + lane]);
            float g1 = bf2f(xwb[(size_t)(e1.x & 0xFFFF) * OUT_DIM + lane]);
            float g2 = bf2f(xwb[(size_t)(e2.x & 0xFFFF) * OUT_DIM + lane]);
            float g3 = bf2f(xwb[(size_t)(e3.x & 0xFFFF) * OUT_DIM + lane]);
            float g4 = bf2f(xwb[(size_t)(e4.x & 0xFFFF) * OUT_DIM + lane]);
            float g5 = bf2f(xwb[(size_t)(e5.x & 0xFFFF) * OUT_DIM + lane]);
            float g6 = bf2f(xwb[(size_t)(e6.x & 0xFFFF) * OUT_DIM + lane]);
            float g7 = bf2f(xwb[(size_t)(e7.x & 0xFFFF) * OUT_DIM + lane]);
            a0 = fmaf(__uint_as_float(e0.y), g0, a0);
            a1 = fmaf(__uint_as_float(e1.y), g1, a1);
            a0 = fmaf(__uint_as_float(e2.y), g2, a0);
            a1 = fmaf(__uint_as_float(e3.y), g3, a1);
            a0 = fmaf(__uint_as_float(e4.y), g4, a0);
            a1 = fmaf(__uint_as_float(e5.y), g5, a1);
            a0 = fmaf(__uint_as_float(e6.y), g6, a0);
            a1 = fmaf(__uint_as_float(e7.y), g7, a1);
        }
        for (; j + 4 <= end; j += 4) {
            uint2 e0 = stage[j], e1 = stage[j+1], e2 = stage[j+2], e3 = stage[j+3];
            float g0 = bf2f(xwb[(size_t)(e0.x & 0xFFFF) * OUT_DIM + lane]);
            float g1 = bf2f(xwb[(size_t)(e1.x & 0xFFFF) * OUT_DIM + lane]);
            float g2 = bf2f(xwb[(size_t)(e2.x & 0xFFFF) * OUT_DIM + lane]);
            float g3 = bf2f(xwb[(size_t)(e3.x & 0xFFFF) * OUT_DIM + lane]);
            a0 = fmaf(__uint_as_float(e0.y), g0, a0);
            a1 = fmaf(__uint_as_float(e1.y), g1, a1);
            a0 = fmaf(__uint_as_float(e2.y), g2, a0);
            a1 = fmaf(__uint_as_float(e3.y), g3, a1);
        }
        for (; j < end; ++j) {
            uint2 e0 = stage[j];
            a0 = fmaf(__uint_as_float(e0.y),
                      bf2f(xwb[(size_t)(e0.x & 0xFFFF) * OUT_DIM + lane]), a0);
        }
        acc[lr] = a0 + a1;
    }

    // overflow contributions (oc == 0 in practice; one uniform load)
    const int oc = *ocount;
    for (int i = 0; i < oc; ++i) {
        const uint4 e = olist[i];
        const int lr = (int)e.x - r0 - wv * 8;
        if (lr >= 0 && lr < 8)
            acc[lr] += __uint_as_float(e.z) *
                       bf2f(xwb[(size_t)e.y * OUT_DIM + lane]);
    }

#pragma unroll
    for (int lr = 0; lr < 8; ++lr) {
        const int row = r0 + wv * 8 + lr;
        if (row < N) {
            const float v = acc[lr];
            out[(size_t)row * OUT_DIM + lane] = v > 0.f ? v : 0.f;
        }
    }
}

// ---------------------------------------------------------------------------
// Fallback: gemm + atomic scatter + relu (always correct).
// ---------------------------------------------------------------------------
__global__ __launch_bounds__(256) void scatter_edges(
        const int* __restrict__ arow, const int* __restrict__ acol,
        const float* __restrict__ aval, const unsigned short* __restrict__ xwb,
        float* __restrict__ out, int E) {
    const int lane = threadIdx.x & 63;
    int gw = (blockIdx.x * 256 + (int)threadIdx.x) >> 6;
    const int nw = (gridDim.x * 256) >> 6;
    for (int e = gw; e < E; e += nw) {
        const float m = aval[e] * bf2f(xwb[(size_t)acol[e] * OUT_DIM + lane]);
        atomicAdd(&out[(size_t)arow[e] * OUT_DIM + lane], m);
    }
}

__global__ __launch_bounds__(256) void relu_inplace(float* __restrict__ o, int n4) {
    float4* p = (float4*)o;
    int i = blockIdx.x * 256 + threadIdx.x;
    const int stride = gridDim.x * 256;
    for (; i < n4; i += stride) {
        float4 v = p[i];
        v.x = v.x > 0.f ? v.x : 0.f;
        v.y = v.y > 0.f ? v.y : 0.f;
        v.z = v.z > 0.f ? v.z : 0.f;
        v.w = v.w > 0.f ? v.w : 0.f;
        p[i] = v;
    }
}

static inline size_t align256(size_t x) { return (x + 255) & ~(size_t)255; }

extern "C" void kernel_launch(void* const* d_in, const int* in_sizes, int n_in,
                              void* d_out, int out_size, void* d_ws, size_t ws_size,
                              hipStream_t stream) {
    const float* x    = (const float*)d_in[0];
    const float* w    = (const float*)d_in[1];
    const int*   arow = (const int*)d_in[2];
    const int*   acol = (const int*)d_in[3];
    const float* aval = (const float*)d_in[4];
    float*       out  = (float*)d_out;

    const int N  = in_sizes[0] / IN_DIM;   // 50000
    const int E  = in_sizes[2];            // 800000
    const int NB = (N + RB - 1) >> RBSH;   // 782
    const int GB = (N + 63) / 64;          // gemm blocks

    char* ws = (char*)d_ws;
    const size_t szXW  = align256((size_t)N * OUT_DIM * sizeof(unsigned short));
    const size_t szCnt = align256((size_t)(NB + 1) * sizeof(int));   // pcur + ocount
    const size_t szOl  = align256((size_t)E * sizeof(uint4));        // olist sized E
    const size_t szPay = (size_t)NB * CAPB * sizeof(uint2);
    const size_t need0 = szXW + szCnt + szOl + szPay;

    unsigned short* xwb = (unsigned short*)ws;
    int*   pcur    = (int*)(ws + szXW);
    int*   ocount  = pcur + NB;
    uint4* olist   = (uint4*)(ws + szXW + szCnt);
    uint2* payload = (uint2*)(ws + szXW + szCnt + szOl);

    if (ws_size >= need0 && N <= 65536 && NB <= 1024) {
        (void)hipMemsetAsync(pcur, 0, (size_t)(NB + 1) * sizeof(int), stream);
        const int chunk = (E + AB2 - 1) / AB2;
        gemm_afill<<<AB2 + GB, 256, 0, stream>>>(x, w, xwb, N, arow, acol, aval,
                                                 pcur, ocount, olist, payload,
                                                 E, NB, chunk);
        bagg3<<<NB, 512, 0, stream>>>(pcur, payload, xwb, out, N, ocount, olist);
    } else {
        gemm_only<<<GB, 256, 0, stream>>>(x, w, xwb, N);
        (void)hipMemsetAsync(d_out, 0, (size_t)out_size * sizeof(float), stream);
        scatter_edges<<<4096, 256, 0, stream>>>(arow, acol, aval, xwb, out, E);
        relu_inplace<<<2048, 256, 0, stream>>>(out, out_size / 4);
    }
}